// Round 2
// 535.919 us; speedup vs baseline: 1.0112x; 1.0112x over previous
//
#include <hip/hip_runtime.h>

#define F_DIM   128
#define D_DIM   128
#define BATCH_N 8192
#define LN_EPS  1e-5f

#define CHUNKS          16                       // stream blocks per feature
#define ROWS_PER_BLOCK  (BATCH_N / CHUNKS)       // 512 rows
#define ITERS           (ROWS_PER_BLOCK / 8)     // 64 iterations of 8 rows

typedef float fx4 __attribute__((ext_vector_type(4)));   // native vector: OK for nontemporal builtin

// LayerNorm of an affine function of scalar x collapses to closed form:
//   emb - mean = x*Wc + bc          (Wc = W[f]-mean_d W[f], bc = b[f]-mean_d b[f])
//   var        = A x^2 + 2B x + C   (A=mean Wc^2, B=mean Wc*bc, C=mean bc^2)
//   out[d]     = (x*rsq)*Wc[d]*g[d] + rsq*bc[d]*g[d] + beta[d],  rsq=rsqrt(var+eps)
//
// Workspace layout (float):
//   P[128][128] = Wc*gamma      @ ws + 0
//   Q[128][128] = bc*gamma      @ ws + 16384
//   S[128][4]   = {A, 2B, C+eps}@ ws + 32768
// Total 133,120 bytes.

// ---- prep: one wave per feature, shuffle-only reductions, no LDS/barriers ----
__global__ __launch_bounds__(64) void prep_kernel(const float* __restrict__ W,
                                                  const float* __restrict__ b,
                                                  const float* __restrict__ gamma,
                                                  float* __restrict__ ws) {
    const int f = blockIdx.x;
    const int t = threadIdx.x;

    const float2 w2 = ((const float2*)W)[f * 64 + t];
    const float2 b2 = ((const float2*)b)[f * 64 + t];
    const float2 g2 = ((const float2*)gamma)[t];

    float sw = w2.x + w2.y;
    float sb = b2.x + b2.y;
    #pragma unroll
    for (int off = 32; off > 0; off >>= 1) {
        sw += __shfl_xor(sw, off);
        sb += __shfl_xor(sb, off);
    }
    const float inv = 1.0f / 128.0f;
    const float mw = sw * inv;
    const float mb = sb * inv;

    const float wcx = w2.x - mw, wcy = w2.y - mw;
    const float bcx = b2.x - mb, bcy = b2.y - mb;

    float a  = wcx * wcx + wcy * wcy;
    float bm = wcx * bcx + wcy * bcy;
    float c  = bcx * bcx + bcy * bcy;
    #pragma unroll
    for (int off = 32; off > 0; off >>= 1) {
        a  += __shfl_xor(a, off);
        bm += __shfl_xor(bm, off);
        c  += __shfl_xor(c, off);
    }

    float* P = ws;
    float* Q = ws + 128 * 128;
    float* S = ws + 2 * 128 * 128;
    ((float2*)P)[f * 64 + t] = make_float2(wcx * g2.x, wcy * g2.y);
    ((float2*)Q)[f * 64 + t] = make_float2(bcx * g2.x, bcy * g2.y);
    if (t == 0) {
        S[f * 4 + 0] = a * inv;
        S[f * 4 + 1] = 2.0f * bm * inv;
        S[f * 4 + 2] = c * inv + LN_EPS;
    }
}

// ---- stream: barrier-free, LDS-free store streamer. 2048 blocks co-resident. ----
__global__ __launch_bounds__(256) void stream_kernel(const float* __restrict__ x,
                                                     const float* __restrict__ beta,
                                                     const float* __restrict__ ws,
                                                     float* __restrict__ out) {
    const int f     = blockIdx.x >> 4;                  // CHUNKS = 16
    const int nbase = (blockIdx.x & (CHUNKS - 1)) * ROWS_PER_BLOCK;
    const int dv    = threadIdx.x & 31;                 // float4 index within d-row
    const int r0    = threadIdx.x >> 5;                 // 0..7: row within 8-row group

    const float4* P4 = (const float4*)ws + f * 32;
    const float4* Q4 = (const float4*)(ws + 128 * 128) + f * 32;
    const float*  S  = ws + 2 * 128 * 128 + f * 4;

    const float4 w0 = P4[dv];
    const float4 b0 = Q4[dv];
    const float4 e0 = ((const float4*)beta)[dv];
    const float  A  = S[0];
    const float  B2 = S[1];
    const float  Cp = S[2];

    const float* xp = x + (nbase + r0) * F_DIM + f;     // advances 8 rows / iter
    fx4* op = (fx4*)out + (size_t)(f * BATCH_N + nbase + r0) * 32 + dv;

    #pragma unroll 4
    for (int it = 0; it < ITERS; ++it) {
        const float xf = xp[it * 8 * F_DIM];

        float var = fmaf(xf, fmaf(xf, A, B2), Cp);
        var = fmaxf(var, 1e-7f);                        // guard fp32 rounding
        const float rsq = rsqrtf(var);
        const float xr  = xf * rsq;

        fx4 o;
        o.x = fmaf(xr, w0.x, fmaf(rsq, b0.x, e0.x));
        o.y = fmaf(xr, w0.y, fmaf(rsq, b0.y, e0.y));
        o.z = fmaf(xr, w0.z, fmaf(rsq, b0.z, e0.z));
        o.w = fmaf(xr, w0.w, fmaf(rsq, b0.w, e0.w));

        __builtin_nontemporal_store(o, op + it * 8 * 32);   // wave = 1 KiB contiguous
    }
}

extern "C" void kernel_launch(void* const* d_in, const int* in_sizes, int n_in,
                              void* d_out, int out_size, void* d_ws, size_t ws_size,
                              hipStream_t stream) {
    const float* x     = (const float*)d_in[0];
    const float* W     = (const float*)d_in[1];
    const float* b     = (const float*)d_in[2];
    const float* gamma = (const float*)d_in[3];
    const float* beta  = (const float*)d_in[4];
    float* out = (float*)d_out;
    float* ws  = (float*)d_ws;
    (void)in_sizes; (void)n_in; (void)out_size; (void)ws_size;

    prep_kernel<<<dim3(F_DIM), dim3(64), 0, stream>>>(W, b, gamma, ws);
    stream_kernel<<<dim3(F_DIM * CHUNKS), dim3(256), 0, stream>>>(x, beta, ws, out);
}

// Round 3
// 534.885 us; speedup vs baseline: 1.0131x; 1.0019x over previous
//
#include <hip/hip_runtime.h>

#define F_DIM   128
#define D_DIM   128
#define BATCH_N 8192
#define LN_EPS  1e-5f

#define CHUNKS          32                       // stream blocks per feature
#define ROWS_PER_BLOCK  (BATCH_N / CHUNKS)       // 256 rows
#define ITERS           (ROWS_PER_BLOCK / 16)    // 16 iterations of 16 rows

typedef float fx4 __attribute__((ext_vector_type(4)));   // native vector: OK for nontemporal builtin

// LayerNorm of an affine function of scalar x collapses to closed form:
//   emb - mean = x*Wc + bc          (Wc = W[f]-mean_d W[f], bc = b[f]-mean_d b[f])
//   var        = A x^2 + 2B x + C   (A=mean Wc^2, B=mean Wc*bc, C=mean bc^2)
//   out[d]     = (x*rsq)*Wc[d]*g[d] + rsq*bc[d]*g[d] + beta[d],  rsq=rsqrt(var+eps)
//
// Workspace layout (float):
//   P[128][128] = Wc*gamma      @ ws + 0
//   Q[128][128] = bc*gamma      @ ws + 16384
//   S[128][4]   = {A, 2B, C+eps}@ ws + 32768

// ---- prep: one wave per feature, shuffle-only reductions, no LDS/barriers ----
__global__ __launch_bounds__(64) void prep_kernel(const float* __restrict__ W,
                                                  const float* __restrict__ b,
                                                  const float* __restrict__ gamma,
                                                  float* __restrict__ ws) {
    const int f = blockIdx.x;
    const int t = threadIdx.x;

    const float2 w2 = ((const float2*)W)[f * 64 + t];
    const float2 b2 = ((const float2*)b)[f * 64 + t];
    const float2 g2 = ((const float2*)gamma)[t];

    float sw = w2.x + w2.y;
    float sb = b2.x + b2.y;
    #pragma unroll
    for (int off = 32; off > 0; off >>= 1) {
        sw += __shfl_xor(sw, off);
        sb += __shfl_xor(sb, off);
    }
    const float inv = 1.0f / 128.0f;
    const float mw = sw * inv;
    const float mb = sb * inv;

    const float wcx = w2.x - mw, wcy = w2.y - mw;
    const float bcx = b2.x - mb, bcy = b2.y - mb;

    float a  = wcx * wcx + wcy * wcy;
    float bm = wcx * bcx + wcy * bcy;
    float c  = bcx * bcx + bcy * bcy;
    #pragma unroll
    for (int off = 32; off > 0; off >>= 1) {
        a  += __shfl_xor(a, off);
        bm += __shfl_xor(bm, off);
        c  += __shfl_xor(c, off);
    }

    float* P = ws;
    float* Q = ws + 128 * 128;
    float* S = ws + 2 * 128 * 128;
    ((float2*)P)[f * 64 + t] = make_float2(wcx * g2.x, wcy * g2.y);
    ((float2*)Q)[f * 64 + t] = make_float2(bcx * g2.x, bcy * g2.y);
    if (t == 0) {
        S[f * 4 + 0] = a * inv;
        S[f * 4 + 1] = 2.0f * bm * inv;
        S[f * 4 + 2] = c * inv + LN_EPS;
    }
}

// ---- stream: barrier-free, LDS-free. 32 B/lane/iter, wave = 2 KiB contiguous ----
__global__ __launch_bounds__(256) void stream_kernel(const float* __restrict__ x,
                                                     const float* __restrict__ beta,
                                                     const float* __restrict__ ws,
                                                     float* __restrict__ out) {
    const int f     = blockIdx.x >> 5;                  // CHUNKS = 32
    const int nbase = (blockIdx.x & (CHUNKS - 1)) * ROWS_PER_BLOCK;
    const int dv    = threadIdx.x & 15;                 // float4 index (this lane covers dv and dv+16)
    const int r0    = threadIdx.x >> 4;                 // 0..15: row within 16-row group

    const float4* P4 = (const float4*)ws + f * 32;
    const float4* Q4 = (const float4*)(ws + 128 * 128) + f * 32;
    const float*  S  = ws + 2 * 128 * 128 + f * 4;

    const float4 w0 = P4[dv];
    const float4 w1 = P4[dv + 16];
    const float4 b0 = Q4[dv];
    const float4 b1 = Q4[dv + 16];
    const float4 e0 = ((const float4*)beta)[dv];
    const float4 e1 = ((const float4*)beta)[dv + 16];
    const float  A  = S[0];
    const float  B2 = S[1];
    const float  Cp = S[2];

    const float* xp = x + (nbase + r0) * F_DIM + f;     // advances 16 rows / iter
    fx4* op = (fx4*)out + (size_t)(f * BATCH_N + nbase + r0) * 32 + dv;

    #pragma unroll 4
    for (int it = 0; it < ITERS; ++it) {
        const float xf = xp[it * 16 * F_DIM];

        float var = fmaf(xf, fmaf(xf, A, B2), Cp);
        var = fmaxf(var, 1e-7f);                        // guard fp32 rounding
        const float rsq = rsqrtf(var);
        const float xr  = xf * rsq;

        fx4 o0, o1;
        o0.x = fmaf(xr, w0.x, fmaf(rsq, b0.x, e0.x));
        o0.y = fmaf(xr, w0.y, fmaf(rsq, b0.y, e0.y));
        o0.z = fmaf(xr, w0.z, fmaf(rsq, b0.z, e0.z));
        o0.w = fmaf(xr, w0.w, fmaf(rsq, b0.w, e0.w));
        o1.x = fmaf(xr, w1.x, fmaf(rsq, b1.x, e1.x));
        o1.y = fmaf(xr, w1.y, fmaf(rsq, b1.y, e1.y));
        o1.z = fmaf(xr, w1.z, fmaf(rsq, b1.z, e1.z));
        o1.w = fmaf(xr, w1.w, fmaf(rsq, b1.w, e1.w));

        __builtin_nontemporal_store(o0, op + it * 16 * 32);        // rows 16/iter: +512 float4
        __builtin_nontemporal_store(o1, op + it * 16 * 32 + 16);
    }
}

extern "C" void kernel_launch(void* const* d_in, const int* in_sizes, int n_in,
                              void* d_out, int out_size, void* d_ws, size_t ws_size,
                              hipStream_t stream) {
    const float* x     = (const float*)d_in[0];
    const float* W     = (const float*)d_in[1];
    const float* b     = (const float*)d_in[2];
    const float* gamma = (const float*)d_in[3];
    const float* beta  = (const float*)d_in[4];
    float* out = (float*)d_out;
    float* ws  = (float*)d_ws;
    (void)in_sizes; (void)n_in; (void)out_size; (void)ws_size;

    prep_kernel<<<dim3(F_DIM), dim3(64), 0, stream>>>(W, b, gamma, ws);
    stream_kernel<<<dim3(F_DIM * CHUNKS), dim3(256), 0, stream>>>(x, beta, ws, out);
}

// Round 4
// 531.894 us; speedup vs baseline: 1.0188x; 1.0056x over previous
//
#include <hip/hip_runtime.h>

#define F_DIM   128
#define D_DIM   128
#define BATCH_N 8192
#define LN_EPS  1e-5f

#define CHUNKS          32                       // stream blocks per feature
#define ROWS_PER_BLOCK  (BATCH_N / CHUNKS)       // 256 rows
#define ITERS           (ROWS_PER_BLOCK / 16)    // 16 iterations of 16 rows

// LayerNorm of an affine function of scalar x collapses to closed form:
//   emb - mean = x*Wc + bc          (Wc = W[f]-mean_d W[f], bc = b[f]-mean_d b[f])
//   var        = A x^2 + 2B x + C   (A=mean Wc^2, B=mean Wc*bc, C=mean bc^2)
//   out[d]     = (x*rsq)*Wc[d]*g[d] + rsq*bc[d]*g[d] + beta[d],  rsq=rsqrt(var+eps)
//
// Workspace layout (float):
//   P[128][128] = Wc*gamma      @ ws + 0
//   Q[128][128] = bc*gamma      @ ws + 16384
//   S[128][4]   = {A, 2B, C+eps}@ ws + 32768

// ---- prep: one wave per feature, shuffle-only reductions, no LDS/barriers ----
__global__ __launch_bounds__(64) void prep_kernel(const float* __restrict__ W,
                                                  const float* __restrict__ b,
                                                  const float* __restrict__ gamma,
                                                  float* __restrict__ ws) {
    const int f = blockIdx.x;
    const int t = threadIdx.x;

    const float2 w2 = ((const float2*)W)[f * 64 + t];
    const float2 b2 = ((const float2*)b)[f * 64 + t];
    const float2 g2 = ((const float2*)gamma)[t];

    float sw = w2.x + w2.y;
    float sb = b2.x + b2.y;
    #pragma unroll
    for (int off = 32; off > 0; off >>= 1) {
        sw += __shfl_xor(sw, off);
        sb += __shfl_xor(sb, off);
    }
    const float inv = 1.0f / 128.0f;
    const float mw = sw * inv;
    const float mb = sb * inv;

    const float wcx = w2.x - mw, wcy = w2.y - mw;
    const float bcx = b2.x - mb, bcy = b2.y - mb;

    float a  = wcx * wcx + wcy * wcy;
    float bm = wcx * bcx + wcy * bcy;
    float c  = bcx * bcx + bcy * bcy;
    #pragma unroll
    for (int off = 32; off > 0; off >>= 1) {
        a  += __shfl_xor(a, off);
        bm += __shfl_xor(bm, off);
        c  += __shfl_xor(c, off);
    }

    float* P = ws;
    float* Q = ws + 128 * 128;
    float* S = ws + 2 * 128 * 128;
    ((float2*)P)[f * 64 + t] = make_float2(wcx * g2.x, wcy * g2.y);
    ((float2*)Q)[f * 64 + t] = make_float2(bcx * g2.x, bcy * g2.y);
    if (t == 0) {
        S[f * 4 + 0] = a * inv;
        S[f * 4 + 1] = 2.0f * bm * inv;
        S[f * 4 + 2] = c * inv + LN_EPS;
    }
}

// ---- stream: barrier-free, LDS-free. x prefetched to regs; pure store stream. ----
__global__ __launch_bounds__(256) void stream_kernel(const float* __restrict__ x,
                                                     const float* __restrict__ beta,
                                                     const float* __restrict__ ws,
                                                     float* __restrict__ out) {
    const int f     = blockIdx.x >> 5;                  // CHUNKS = 32
    const int nbase = (blockIdx.x & (CHUNKS - 1)) * ROWS_PER_BLOCK;
    const int dv    = threadIdx.x & 15;                 // float4 index (lane covers dv and dv+16)
    const int r0    = threadIdx.x >> 4;                 // 0..15: row within 16-row group

    const float4* P4 = (const float4*)ws + f * 32;
    const float4* Q4 = (const float4*)(ws + 128 * 128) + f * 32;
    const float*  S  = ws + 2 * 128 * 128 + f * 4;

    const float4 w0 = P4[dv];
    const float4 w1 = P4[dv + 16];
    const float4 b0 = Q4[dv];
    const float4 b1 = Q4[dv + 16];
    const float4 e0 = ((const float4*)beta)[dv];
    const float4 e1 = ((const float4*)beta)[dv + 16];
    const float  A  = S[0];
    const float  B2 = S[1];
    const float  Cp = S[2];

    // Prefetch all x values for this thread (compile-time-indexed -> stays in VGPRs,
    // 16 independent loads issue up front; latency hidden under the store stream).
    const float* xp = x + (nbase + r0) * F_DIM + f;
    float xs[ITERS];
    #pragma unroll
    for (int it = 0; it < ITERS; ++it) xs[it] = xp[it * 16 * F_DIM];

    float4* op = (float4*)out + (size_t)(f * BATCH_N + nbase + r0) * 32 + dv;

    #pragma unroll
    for (int it = 0; it < ITERS; ++it) {
        const float xf = xs[it];

        float var = fmaf(xf, fmaf(xf, A, B2), Cp);
        var = fmaxf(var, 1e-7f);                        // guard fp32 rounding
        const float rsq = rsqrtf(var);
        const float xr  = xf * rsq;

        float4 o0, o1;
        o0.x = fmaf(xr, w0.x, fmaf(rsq, b0.x, e0.x));
        o0.y = fmaf(xr, w0.y, fmaf(rsq, b0.y, e0.y));
        o0.z = fmaf(xr, w0.z, fmaf(rsq, b0.z, e0.z));
        o0.w = fmaf(xr, w0.w, fmaf(rsq, b0.w, e0.w));
        o1.x = fmaf(xr, w1.x, fmaf(rsq, b1.x, e1.x));
        o1.y = fmaf(xr, w1.y, fmaf(rsq, b1.y, e1.y));
        o1.z = fmaf(xr, w1.z, fmaf(rsq, b1.z, e1.z));
        o1.w = fmaf(xr, w1.w, fmaf(rsq, b1.w, e1.w));

        op[it * 16 * 32]      = o0;                     // regular stores: match the
        op[it * 16 * 32 + 16] = o1;                     // 6.3 TB/s fill path (no nt)
    }
}

extern "C" void kernel_launch(void* const* d_in, const int* in_sizes, int n_in,
                              void* d_out, int out_size, void* d_ws, size_t ws_size,
                              hipStream_t stream) {
    const float* x     = (const float*)d_in[0];
    const float* W     = (const float*)d_in[1];
    const float* b     = (const float*)d_in[2];
    const float* gamma = (const float*)d_in[3];
    const float* beta  = (const float*)d_in[4];
    float* out = (float*)d_out;
    float* ws  = (float*)d_ws;
    (void)in_sizes; (void)n_in; (void)out_size; (void)ws_size;

    prep_kernel<<<dim3(F_DIM), dim3(64), 0, stream>>>(W, b, gamma, ws);
    stream_kernel<<<dim3(F_DIM * CHUNKS), dim3(256), 0, stream>>>(x, beta, ws, out);
}